// Round 1
// baseline (585.819 us; speedup 1.0000x reference)
//
#include <hip/hip_runtime.h>
#include <hip/hip_bf16.h>
#include <math.h>

typedef __bf16 bf16x8 __attribute__((ext_vector_type(8)));
typedef __bf16 bf16x4 __attribute__((ext_vector_type(4)));
typedef float f32x4 __attribute__((ext_vector_type(4)));

static __device__ __forceinline__ f32x4 mfma16(bf16x8 a, bf16x8 b, f32x4 c) {
  return __builtin_amdgcn_mfma_f32_16x16x32_bf16(a, b, c, 0, 0, 0);
}

// ---------------- ws byte layout ----------------
// 0      : wq_pk  [kt4][dt8][lane64][8] bf16  (scale folded)   32768 B
// 32768  : wk_pk  [kt4][dt8][lane64][8] bf16                   32768 B
// 65536  : wv_pk  [kt4][dt8][lane64][8] bf16                   32768 B
// 98304  : f1_pk  [kt4][ht2][lane64][8] bf16 (fc1^T A-frags)    8192 B
// 106496 : f2_pk  [dt8][lane64][8] bf16 (fc2 B-frags)           8192 B
// 114688 : biasT  [h4][mt4][nt4][lane64] float4                65536 B
// 180224 : bq_s   [128] float (bq*scale)                         512 B
// total 180736 B

__global__ void wattn_prep(const float* __restrict__ wq, const float* __restrict__ bq,
                           const float* __restrict__ wkv,
                           const float* __restrict__ f1w, const float* __restrict__ f2w,
                           const float* __restrict__ rpb, const int* __restrict__ rel,
                           char* __restrict__ ws)
{
  const int idx = blockIdx.x * 256 + threadIdx.x;
  const float scale = 0.17677669529663687f; // 32^-0.5
  unsigned short* ws16 = (unsigned short*)ws;
  float* wsf = (float*)ws;

  if (idx < 2048) {                       // wq_pk (A-frag of Wq^T == B-frag of Wq), *scale
    const int lane = idx & 63, dt = (idx >> 6) & 7, kt = idx >> 9;
    const int gg = lane >> 4, cc = lane & 15;
    bf16x8 v;
#pragma unroll
    for (int i = 0; i < 8; ++i)
      v[i] = (__bf16)(wq[(kt * 32 + gg * 8 + i) * 128 + dt * 16 + cc] * scale);
    *(bf16x8*)(ws16 + idx * 8) = v;
  } else if (idx < 4096) {                // wk_pk (K columns of wkv)
    const int e = idx - 2048;
    const int lane = e & 63, dt = (e >> 6) & 7, kt = e >> 9;
    const int gg = lane >> 4, cc = lane & 15;
    bf16x8 v;
#pragma unroll
    for (int i = 0; i < 8; ++i)
      v[i] = (__bf16)(wkv[(kt * 32 + gg * 8 + i) * 256 + dt * 16 + cc]);
    *(bf16x8*)(ws16 + 16384 + e * 8) = v;
  } else if (idx < 6144) {                // wv_pk (V columns of wkv)
    const int e = idx - 4096;
    const int lane = e & 63, dt = (e >> 6) & 7, kt = e >> 9;
    const int gg = lane >> 4, cc = lane & 15;
    bf16x8 v;
#pragma unroll
    for (int i = 0; i < 8; ++i)
      v[i] = (__bf16)(wkv[(kt * 32 + gg * 8 + i) * 256 + 128 + dt * 16 + cc]);
    *(bf16x8*)(ws16 + 32768 + e * 8) = v;
  } else if (idx < 6656) {                // f1_pk (fc1^T A-frags)
    const int e = idx - 6144;
    const int lane = e & 63, ht = (e >> 6) & 1, kt = e >> 7;
    const int gg = lane >> 4, cc = lane & 15;
    bf16x8 v;
#pragma unroll
    for (int i = 0; i < 8; ++i)
      v[i] = (__bf16)(f1w[(kt * 32 + gg * 8 + i) * 32 + ht * 16 + cc]);
    *(bf16x8*)(ws16 + 49152 + e * 8) = v;
  } else if (idx < 7168) {                // f2_pk (fc2 B-frags, K=32)
    const int e = idx - 6656;
    const int lane = e & 63, dt = e >> 6;
    const int gg = lane >> 4, cc = lane & 15;
    bf16x8 v;
#pragma unroll
    for (int i = 0; i < 8; ++i)
      v[i] = (__bf16)(f2w[(gg * 8 + i) * 128 + dt * 16 + cc]);
    *(bf16x8*)(ws16 + 53248 + e * 8) = v;
  } else if (idx < 11264) {               // biasT_pk: C-init for S^T = mfma(K,Q)
    const int e = idx - 7168;
    const int lane = e & 63, nt = (e >> 6) & 3, mt = (e >> 8) & 3, h = e >> 10;
    const int gg = lane >> 4, cc = lane & 15;
    const int q = nt * 16 + cc;
    f32x4 v;
#pragma unroll
    for (int r = 0; r < 4; ++r) {
      const int key = mt * 16 + gg * 4 + r;
      v[r] = rpb[rel[q * 64 + key] * 4 + h];
    }
    *(f32x4*)(wsf + 28672 + e * 4) = v;   // byte 114688
  } else if (idx < 11392) {               // bq * scale
    const int d = idx - 11264;
    wsf[45056 + d] = bq[d] * scale;       // byte 180224
  }
}

// LDS regions (dynamic, 65536 B total), with aliasing across phases:
//  R0 [0,16384)      : xb[64][128]bf16 (swz)      -> P slices w=0,1 ([64][64]bf16 each)
//  R1 [16384,32768)  : Q[tok][dim] bf16 (swz)     -> O[tok][dim]
//  R2 [32768,49152)  : K[tok][dim] bf16 (swz)     -> P slices w=2,3
//  R3 [49152,65536)  : V_T[dim][tok] bf16 (swz)   -> H[tok][32]
__global__ __launch_bounds__(256, 2) void wattn_main(
    const float* __restrict__ x,
    const float* __restrict__ bkv,
    const float* __restrict__ f1b,
    const float* __restrict__ f2b,
    const char* __restrict__ ws,
    float* __restrict__ out)
{
  extern __shared__ char smem[];
  const int tid = threadIdx.x;
  const int w = tid >> 6;        // wave id = token-tile / head id
  const int l = tid & 63;
  const int g = l >> 4;
  const int c = l & 15;
  const size_t b = blockIdx.x;

  const unsigned short* ws16 = (const unsigned short*)ws;
  const bf16x8* wqp = (const bf16x8*)(ws16);
  const bf16x8* wkp = (const bf16x8*)(ws16 + 16384);
  const bf16x8* wvp = (const bf16x8*)(ws16 + 32768);
  const bf16x8* f1p = (const bf16x8*)(ws16 + 49152);
  const bf16x8* f2p = (const bf16x8*)(ws16 + 53248);
  const f32x4* biasp = (const f32x4*)(ws16 + 57344);
  const float* bqs = (const float*)(ws16 + 90112);

  // ---- phase 0: stage x (64x128 f32) -> bf16 LDS R0, XOR-swizzled
  {
    const float* xg = x + b * 8192;
#pragma unroll
    for (int i = 0; i < 8; ++i) {
      const int idx = i * 256 + tid;            // float4 index
      f32x4 v = *((const f32x4*)xg + idx);
      const int row = idx >> 5;                 // 32 float4 per row
      const int col = (idx & 31) << 2;
      const int addr = (((row << 8) + (col << 1))) ^ ((row & 7) << 4);
      bf16x4 p = { (__bf16)v[0], (__bf16)v[1], (__bf16)v[2], (__bf16)v[3] };
      *(bf16x4*)(smem + addr) = p;
    }
  }
  __syncthreads();

  // ---- phase 1: projections. x B-frags (tokens w*16+c) reused for Q,K,V.
  bf16x8 xf[4];
  {
    const int row = w * 16 + c;
    const int sw = (row & 7) << 4;
#pragma unroll
    for (int kt = 0; kt < 4; ++kt)
      xf[kt] = *(const bf16x8*)(smem + (((row << 8) + kt * 64 + (g << 4)) ^ sw));
  }
  {
    // Q,K swapped: D[d][t] = sum_k W^T[d][k] X^T[k][t]; write row-major [t][d] -> b64 packs
    const int row = w * 16 + c;
    const int sw = (row & 7) << 4;
#pragma unroll
    for (int dt = 0; dt < 8; ++dt) {
      f32x4 aq = *(const f32x4*)(bqs + dt * 16 + g * 4);
      f32x4 ak = *(const f32x4*)(bkv + dt * 16 + g * 4);
#pragma unroll
      for (int kt = 0; kt < 4; ++kt) {
        aq = mfma16(wqp[(kt * 8 + dt) * 64 + l], xf[kt], aq);
        ak = mfma16(wkp[(kt * 8 + dt) * 64 + l], xf[kt], ak);
      }
      const int addr = (((row << 8) + dt * 32 + g * 8)) ^ sw;
      bf16x4 q4 = { (__bf16)aq[0], (__bf16)aq[1], (__bf16)aq[2], (__bf16)aq[3] };
      bf16x4 k4 = { (__bf16)ak[0], (__bf16)ak[1], (__bf16)ak[2], (__bf16)ak[3] };
      *(bf16x4*)(smem + 16384 + addr) = q4;
      *(bf16x4*)(smem + 32768 + addr) = k4;
    }
  }
  {
    // V direct: D[t][d]; write transposed V_T[d][t] -> b64 packs along t
#pragma unroll
    for (int dt = 0; dt < 8; ++dt) {
      const float bv = bkv[128 + dt * 16 + c];
      f32x4 av = { bv, bv, bv, bv };
#pragma unroll
      for (int kt = 0; kt < 4; ++kt)
        av = mfma16(xf[kt], wvp[(kt * 8 + dt) * 64 + l], av);
      const int row = dt * 16 + c;              // d
      const int addr = (((row << 7) + w * 32 + g * 8)) ^ ((row & 7) << 4);
      bf16x4 v4 = { (__bf16)av[0], (__bf16)av[1], (__bf16)av[2], (__bf16)av[3] };
      *(bf16x4*)(smem + 49152 + addr) = v4;
    }
  }
  __syncthreads();

  // ---- phase 2: attention, head w.  S^T = mfma(K, Q) + biasT
  bf16x8 ka[4], qb[4];
#pragma unroll
  for (int t4 = 0; t4 < 4; ++t4) {
    const int row = t4 * 16 + c;
    const int addr = (((row << 8) + w * 64 + (g << 4))) ^ ((row & 7) << 4);
    ka[t4] = *(const bf16x8*)(smem + 32768 + addr);   // K rows (keys)
    qb[t4] = *(const bf16x8*)(smem + 16384 + addr);   // Q rows (queries)
  }
  f32x4 s[4][4];
#pragma unroll
  for (int mt = 0; mt < 4; ++mt)
#pragma unroll
    for (int nt = 0; nt < 4; ++nt)
      s[mt][nt] = mfma16(ka[mt], qb[nt], biasp[((w * 4 + mt) * 4 + nt) * 64 + l]);
  __syncthreads();   // all Q,K reads done -> R1/R2 reusable

  // softmax over keys: per-lane 16 values + butterfly over g (masks 16,32)
  float rinv[4];
#pragma unroll
  for (int nt = 0; nt < 4; ++nt) {
    float m = s[0][nt][0];
#pragma unroll
    for (int mt = 0; mt < 4; ++mt)
#pragma unroll
      for (int r = 0; r < 4; ++r)
        m = fmaxf(m, s[mt][nt][r]);
    m = fmaxf(m, __shfl_xor(m, 16, 64));
    m = fmaxf(m, __shfl_xor(m, 32, 64));
    float sum = 0.f;
#pragma unroll
    for (int mt = 0; mt < 4; ++mt)
#pragma unroll
      for (int r = 0; r < 4; ++r) {
        const float e = __expf(s[mt][nt][r] - m);
        s[mt][nt][r] = e;
        sum += e;
      }
    sum += __shfl_xor(sum, 16, 64);
    sum += __shfl_xor(sum, 32, 64);
    rinv[nt] = 1.0f / sum;
  }

  // write P[q][key] (unnormalized bf16), 4 consecutive keys per b64
  const int pbase = (w < 2) ? (w * 8192) : (32768 + (w - 2) * 8192);
#pragma unroll
  for (int nt = 0; nt < 4; ++nt) {
    const int row = nt * 16 + c;                // q
    const int sw = (row & 7) << 4;
#pragma unroll
    for (int mt = 0; mt < 4; ++mt) {
      const int addr = (((row << 7) + mt * 32 + g * 8)) ^ sw;
      bf16x4 p4 = { (__bf16)s[mt][nt][0], (__bf16)s[mt][nt][1],
                    (__bf16)s[mt][nt][2], (__bf16)s[mt][nt][3] };
      *(bf16x4*)(smem + pbase + addr) = p4;
    }
  }

  // PV: O^T[d][q] = sum_key V_T[d][key] * P[q][key]^T
  bf16x8 va[2][2], pbf[2][4];
#pragma unroll
  for (int dt2 = 0; dt2 < 2; ++dt2)
#pragma unroll
    for (int ks = 0; ks < 2; ++ks) {
      const int row = (2 * w + dt2) * 16 + c;   // d
      const int addr = (((row << 7) + ks * 64 + (g << 4))) ^ ((row & 7) << 4);
      va[dt2][ks] = *(const bf16x8*)(smem + 49152 + addr);
    }
#pragma unroll
  for (int ks = 0; ks < 2; ++ks)
#pragma unroll
    for (int nt = 0; nt < 4; ++nt) {
      const int row = nt * 16 + c;              // q
      const int addr = (((row << 7) + ks * 64 + (g << 4))) ^ ((row & 7) << 4);
      pbf[ks][nt] = *(const bf16x8*)(smem + pbase + addr);
    }
#pragma unroll
  for (int nt = 0; nt < 4; ++nt) {
    const int row = nt * 16 + c;                // q
    const int sw = (row & 7) << 4;
    const float rv = rinv[nt];
#pragma unroll
    for (int dt2 = 0; dt2 < 2; ++dt2) {
      f32x4 acc = { 0.f, 0.f, 0.f, 0.f };
      acc = mfma16(va[dt2][0], pbf[0][nt], acc);
      acc = mfma16(va[dt2][1], pbf[1][nt], acc);
      const int addr = (((row << 8) + (2 * w + dt2) * 32 + g * 8)) ^ sw;
      bf16x4 o4 = { (__bf16)(acc[0] * rv), (__bf16)(acc[1] * rv),
                    (__bf16)(acc[2] * rv), (__bf16)(acc[3] * rv) };
      *(bf16x4*)(smem + 16384 + addr) = o4;     // O[q][d] in R1
    }
  }
  __syncthreads();   // O complete; V_T reads done -> R3 reusable as H

  // ---- phase 3: MLP on token-tile w
  bf16x8 ob[4];
  {
    const int row = w * 16 + c;
    const int sw = (row & 7) << 4;
#pragma unroll
    for (int kt = 0; kt < 4; ++kt)
      ob[kt] = *(const bf16x8*)(smem + 16384 + (((row << 8) + kt * 64 + (g << 4)) ^ sw));
  }
  {
    // fc1 swapped: D[h][t]; gelu; write H[t][h] (b64 packs along h)
    const int row = w * 16 + c;                 // t
    const int sw = (row & 7) << 4;
#pragma unroll
    for (int ht = 0; ht < 2; ++ht) {
      f32x4 ah = *(const f32x4*)(f1b + ht * 16 + g * 4);
#pragma unroll
      for (int kt = 0; kt < 4; ++kt)
        ah = mfma16(f1p[(kt * 2 + ht) * 64 + l], ob[kt], ah);
      bf16x4 h4;
#pragma unroll
      for (int r = 0; r < 4; ++r) {
        const float v = ah[r];
        h4[r] = (__bf16)(0.5f * v * (1.0f + erff(v * 0.70710678118654752f)));
      }
      *(bf16x4*)(smem + 49152 + (((row << 6) + ht * 32 + g * 8) ^ sw)) = h4;
    }
  }
  bf16x8 ha;
  {
    const int row = w * 16 + c;
    ha = *(const bf16x8*)(smem + 49152 + (((row << 6) + (g << 4)) ^ ((row & 7) << 4)));
  }
  {
    // fc2 direct: D[t][d] + fc2_b -> global (64B segments per 16 lanes)
    float* og = out + b * 8192 + (size_t)(w * 16) * 128;
#pragma unroll
    for (int dt = 0; dt < 8; ++dt) {
      const float bb = f2b[dt * 16 + c];
      f32x4 ay = { bb, bb, bb, bb };
      ay = mfma16(ha, f2p[dt * 64 + l], ay);
#pragma unroll
      for (int r = 0; r < 4; ++r)
        og[(g * 4 + r) * 128 + dt * 16 + c] = ay[r];
    }
  }
}

extern "C" void kernel_launch(void* const* d_in, const int* in_sizes, int n_in,
                              void* d_out, int out_size, void* d_ws, size_t ws_size,
                              hipStream_t stream) {
  const float* x    = (const float*)d_in[0];
  const float* rpb  = (const float*)d_in[1];
  const float* wq   = (const float*)d_in[2];
  const float* bq   = (const float*)d_in[3];
  const float* wkv  = (const float*)d_in[4];
  const float* bkv  = (const float*)d_in[5];
  const float* f1w  = (const float*)d_in[6];
  const float* f1b  = (const float*)d_in[7];
  const float* f2w  = (const float*)d_in[8];
  const float* f2b  = (const float*)d_in[9];
  const int*   rel  = (const int*)d_in[10];
  float* out = (float*)d_out;
  char* ws = (char*)d_ws;
  if (ws_size < 180736) return;

  const int nB = in_sizes[0] / 8192;   // 16384 windows

  wattn_prep<<<45, 256, 0, stream>>>(wq, bq, wkv, f1w, f2w, rpb, rel, ws);
  wattn_main<<<nB, 256, 65536, stream>>>(x, bkv, f1b, f2b, ws, out);
}